// Round 1
// baseline (1439.803 us; speedup 1.0000x reference)
//
#include <hip/hip_runtime.h>
#include <math.h>

#define HW 16384
#define IMG 128
#define CDIM 192
#define C3 144
#define C4 48
#define NB 2
#define NPX 32768   // NB*HW
#define HEADS 6

static inline float* wsf(void* ws, size_t off) { return (float*)((char*)ws + off); }

// ---------------- K0: tiny GEMVs for modulation scales (stored as val+1) ----
__global__ void k_gemv(const float* __restrict__ kvv, const float* __restrict__ wkR,
                       const float* __restrict__ wkI, const float* __restrict__ wffk,
                       float* __restrict__ sm) {
    int t = blockIdx.x * 256 + threadIdx.x;  // 0..767
    if (t < 288) {                       // kvr: [2][144]
        int b = t / 144, o = t % 144;
        const float* v = kvv + b * 256;
        const float* w = wkR + o * 192;
        float s = 0.f;
        for (int j = 0; j < 192; j++) s += v[j] * w[j];
        sm[t] = s + 1.0f;
    } else if (t < 384) {                // kvi: [2][48] at sm+288
        int r = t - 288;
        int b = r / 48, o = r % 48;
        const float* v = kvv + b * 256 + 192;
        const float* w = wkI + o * 64;
        float s = 0.f;
        for (int j = 0; j < 64; j++) s += v[j] * w[j];
        sm[288 + r] = s + 1.0f;
    } else if (t < 768) {                // kvf: [2][192] at sm+384
        int r = t - 384;
        int b = r / 192, o = r % 192;
        const float* v = kvv + b * 256;
        const float* w = wffk + o * 256;
        float s = 0.f;
        for (int j = 0; j < 256; j++) s += v[j] * w[j];
        sm[384 + r] = s + 1.0f;
    }
}

// ---------------- K1: per-pixel channel LayerNorm + modulation ---------------
// outB != nullptr: split 144/48 (attention path). else: full 192 channels.
__global__ __launch_bounds__(256) void k_ln_mod(
    const float* __restrict__ x, const float* __restrict__ lnw, const float* __restrict__ lnb,
    const float* __restrict__ sca, const float* __restrict__ scb,
    float* __restrict__ outA, float* __restrict__ outB) {
    int g = blockIdx.x * 256 + threadIdx.x;  // < NPX
    int b = g >> 14, p = g & 16383;
    const float* xp = x + (size_t)b * CDIM * HW + p;
    float s = 0.f, s2 = 0.f;
    for (int c = 0; c < CDIM; c++) { float v = xp[(size_t)c * HW]; s += v; s2 += v * v; }
    float mu = s * (1.0f / CDIM);
    float var = s2 * (1.0f / CDIM) - mu * mu;
    float rstd = rsqrtf(var + 1e-5f);
    if (outB) {
        for (int c = 0; c < C3; c++) {
            float v = xp[(size_t)c * HW];
            float xn = (v - mu) * rstd * lnw[c] + lnb[c];
            outA[((size_t)b * C3 + c) * HW + p] = xn * sca[b * C3 + c];
        }
        for (int c = 0; c < C4; c++) {
            float v = xp[(size_t)(C3 + c) * HW];
            float xn = (v - mu) * rstd * lnw[C3 + c] + lnb[C3 + c];
            outB[((size_t)b * C4 + c) * HW + p] = xn * scb[b * C4 + c];
        }
    } else {
        for (int c = 0; c < CDIM; c++) {
            float v = xp[(size_t)c * HW];
            float xn = (v - mu) * rstd * lnw[c] + lnb[c];
            outA[((size_t)b * CDIM + c) * HW + p] = xn * sca[b * CDIM + c];
        }
    }
}

// ---------------- K2: conv1x1 (pointwise GEMM), LDS pixel tile ---------------
template <int CI, int TILE_P, int PJ>
__global__ __launch_bounds__(256) void k_conv1x1(
    const float* __restrict__ X, const float* __restrict__ W,
    const float* __restrict__ resid, float* __restrict__ out, int Co) {
    __shared__ float Xs[CI * TILE_P];
    int tid = threadIdx.x;
    int px0 = blockIdx.x * TILE_P;
    int b = px0 >> 14;
    int pl0 = px0 & 16383;
    const float* Xb = X + (size_t)b * CI * HW + pl0;
    for (int idx = tid; idx < CI * TILE_P; idx += 256) {
        int i = idx / TILE_P, pp = idx % TILE_P;
        Xs[idx] = Xb[(size_t)i * HW + pp];
    }
    __syncthreads();
    const int NP = TILE_P / PJ;
    const int NOG = 256 / NP;
    int pl = (tid % NP) * PJ;
    int og = tid / NP;
    for (int o = og; o < Co; o += NOG) {
        float acc[PJ];
#pragma unroll
        for (int j = 0; j < PJ; j++) acc[j] = 0.f;
        const float* wr = W + (size_t)o * CI;
        for (int i = 0; i < CI; i++) {
            float w = wr[i];
            float xv[PJ];
            if constexpr (PJ == 4) {
                *(float4*)xv = *(const float4*)&Xs[i * TILE_P + pl];
            } else if constexpr (PJ == 2) {
                *(float2*)xv = *(const float2*)&Xs[i * TILE_P + pl];
            } else {
                xv[0] = Xs[i * TILE_P + pl];
            }
#pragma unroll
            for (int j = 0; j < PJ; j++) acc[j] += w * xv[j];
        }
        size_t ob = ((size_t)b * Co + o) * HW + pl0 + pl;
        if (resid) {
#pragma unroll
            for (int j = 0; j < PJ; j++) acc[j] += resid[ob + j];
        }
#pragma unroll
        for (int j = 0; j < PJ; j++) out[ob + j] = acc[j];
    }
}

// ---------------- K3: depthwise 3x3 ------------------------------------------
__global__ __launch_bounds__(256) void k_dw(const float* __restrict__ X,
                                            const float* __restrict__ Wd,
                                            float* __restrict__ out, int Ctot) {
    int g = blockIdx.x * 256 + threadIdx.x;  // < NB*Ctot*HW
    int p = g & 16383;
    int bc = g >> 14;
    int ch = bc % Ctot;
    int py = p >> 7, px = p & 127;
    const float* xb = X + (size_t)bc * HW;
    const float* w = Wd + ch * 9;
    float s = 0.f;
#pragma unroll
    for (int ky = 0; ky < 3; ky++) {
        int y = py + ky - 1;
        if ((unsigned)y >= (unsigned)IMG) continue;
#pragma unroll
        for (int kx = 0; kx < 3; kx++) {
            int x2 = px + kx - 1;
            if ((unsigned)x2 >= (unsigned)IMG) continue;
            s += w[ky * 3 + kx] * xb[y * IMG + x2];
        }
    }
    out[g] = s;
}

// ---------------- K3b: depthwise 3x3 (pair) + exact GELU gate ----------------
__global__ __launch_bounds__(256) void k_dw_gelu(const float* __restrict__ G0,
                                                 const float* __restrict__ Wd,
                                                 float* __restrict__ out) {
    int g = blockIdx.x * 256 + threadIdx.x;  // < NB*384*HW
    int p = g & 16383;
    int bj = g >> 14;
    int b = bj / 384, j = bj % 384;
    int py = p >> 7, px = p & 127;
    const float* x1p = G0 + ((size_t)b * 768 + j) * HW;
    const float* x2p = G0 + ((size_t)b * 768 + 384 + j) * HW;
    const float* w1 = Wd + j * 9;
    const float* w2 = Wd + (384 + j) * 9;
    float s1 = 0.f, s2 = 0.f;
#pragma unroll
    for (int ky = 0; ky < 3; ky++) {
        int y = py + ky - 1;
        if ((unsigned)y >= (unsigned)IMG) continue;
#pragma unroll
        for (int kx = 0; kx < 3; kx++) {
            int x2 = px + kx - 1;
            if ((unsigned)x2 >= (unsigned)IMG) continue;
            int o = y * IMG + x2, k = ky * 3 + kx;
            s1 += w1[k] * x1p[o];
            s2 += w2[k] * x2p[o];
        }
    }
    float a = 0.5f * s1 * (1.0f + erff(s1 * 0.70710678118654752f));
    out[g] = a * s2;
}

// ---------------- K4: per-row inverse L2 norms (q rows, k rows) --------------
__global__ __launch_bounds__(256) void k_rownorm(const float* __restrict__ q,
                                                 const float* __restrict__ kvb,
                                                 float* __restrict__ invq,
                                                 float* __restrict__ invk) {
    int r = blockIdx.x;  // 0..767
    const float* ptr;
    if (r < 384) {
        ptr = q + (size_t)r * HW;
    } else {
        int rc = r - 384;
        int b = rc / 192, c2 = rc % 192;
        ptr = kvb + ((size_t)b * 384 + c2) * HW;  // k = first 192 ch of kv
    }
    float s = 0.f;
    for (int i = threadIdx.x; i < HW; i += 256) { float v = ptr[i]; s += v * v; }
    for (int o = 32; o > 0; o >>= 1) s += __shfl_down(s, o, 64);
    __shared__ float red[4];
    int wid = threadIdx.x >> 6, lane = threadIdx.x & 63;
    if (lane == 0) red[wid] = s;
    __syncthreads();
    if (threadIdx.x == 0) {
        float t = red[0] + red[1] + red[2] + red[3];
        float inv = 1.0f / fmaxf(sqrtf(t), 1e-12f);
        if (r < 384) invq[r] = inv; else invk[r - 384] = inv;
    }
}

// ---------------- K5: S = Q * K^T (raw, unnormalized), d-split + atomics -----
__global__ __launch_bounds__(256) void k_qk(const float* __restrict__ q,
                                            const float* __restrict__ kvb,
                                            float* __restrict__ S) {
    __shared__ float Qs[32 * 64];
    __shared__ float Ks[32 * 65];
    int bh = blockIdx.x >> 5;       // 0..11
    int ds = blockIdx.x & 31;       // 0..31
    int b = bh / HEADS, h = bh % HEADS;
    const float* qb = q + ((size_t)b * CDIM + h * 32) * HW;
    const float* kb = kvb + ((size_t)b * 384 + h * 32) * HW;
    int tid = threadIdx.x;
    int c0 = tid >> 5;   // 0..7
    int e = tid & 31;
    float acc[4] = {0.f, 0.f, 0.f, 0.f};
    int dbeg = ds * 512;
    for (int d0 = dbeg; d0 < dbeg + 512; d0 += 64) {
        for (int idx = tid; idx < 2048; idx += 256) {
            int r = idx >> 6, dd = idx & 63;
            Qs[r * 64 + dd] = qb[(size_t)r * HW + d0 + dd];
            Ks[r * 65 + dd] = kb[(size_t)r * HW + d0 + dd];
        }
        __syncthreads();
        for (int dd = 0; dd < 64; dd++) {
            float kvv = Ks[e * 65 + dd];
#pragma unroll
            for (int k2 = 0; k2 < 4; k2++) acc[k2] += Qs[(c0 + 8 * k2) * 64 + dd] * kvv;
        }
        __syncthreads();
    }
    float* Sb = S + bh * 1024;
#pragma unroll
    for (int k2 = 0; k2 < 4; k2++) atomicAdd(&Sb[(c0 + 8 * k2) * 32 + e], acc[k2]);
}

// ---------------- K6: normalize + temp + softmax over 32 ---------------------
__global__ void k_softmax(const float* __restrict__ S, const float* __restrict__ invq,
                          const float* __restrict__ invk, const float* __restrict__ temp,
                          float* __restrict__ attn) {
    int row = blockIdx.x;           // 0..383
    int bh = row >> 5, c2 = row & 31;
    int b = bh / HEADS, h = bh % HEADS;
    int e = threadIdx.x;            // 64 threads, active e<32
    float l = -1e30f;
    if (e < 32)
        l = S[bh * 1024 + c2 * 32 + e] * invq[b * CDIM + h * 32 + c2] *
            invk[b * CDIM + h * 32 + e] * temp[h];
    float m = l;
    for (int o = 32; o > 0; o >>= 1) m = fmaxf(m, __shfl_xor(m, o, 64));
    float ev = (e < 32) ? expf(l - m) : 0.f;
    float ssum = ev;
    for (int o = 32; o > 0; o >>= 1) ssum += __shfl_xor(ssum, o, 64);
    if (e < 32) attn[bh * 1024 + c2 * 32 + e] = ev / ssum;
}

// ---------------- K7: out = attn @ V -----------------------------------------
__global__ __launch_bounds__(256) void k_av(const float* __restrict__ attn,
                                            const float* __restrict__ kvb,
                                            float* __restrict__ out) {
    __shared__ float As[1024];
    __shared__ float Vs[32 * 128];
    int bh = blockIdx.x >> 7;       // 0..11
    int pt = blockIdx.x & 127;      // pixel tile
    int b = bh / HEADS, h = bh % HEADS;
    int pl0 = pt * 128;
    int tid = threadIdx.x;
    for (int idx = tid; idx < 1024; idx += 256) As[idx] = attn[bh * 1024 + idx];
    const float* vb = kvb + ((size_t)b * 384 + 192 + h * 32) * HW + pl0;
    for (int idx = tid; idx < 4096; idx += 256) {
        int e2 = idx >> 7, pp = idx & 127;
        Vs[idx] = vb[(size_t)e2 * HW + pp];
    }
    __syncthreads();
    int pp = tid & 127;
    int cb = tid >> 7;  // 0..1
    float* ob = out + ((size_t)b * CDIM + h * 32) * HW + pl0;
    for (int k2 = 0; k2 < 16; k2++) {
        int c2 = cb * 16 + k2;
        float s = 0.f;
#pragma unroll 8
        for (int e2 = 0; e2 < 32; e2++) s += As[c2 * 32 + e2] * Vs[e2 * 128 + pp];
        ob[(size_t)c2 * HW + pp] = s;
    }
}

// ---------------- K8: pass k_v through to output tail ------------------------
__global__ void k_copy(const float* __restrict__ kvv, float* __restrict__ out) {
    int t = blockIdx.x * 256 + threadIdx.x;
    if (t < 512) out[t] = kvv[t];
}

extern "C" void kernel_launch(void* const* d_in, const int* in_sizes, int n_in,
                              void* d_out, int out_size, void* d_ws, size_t ws_size,
                              hipStream_t stream) {
    const float* x     = (const float*)d_in[0];
    const float* k_v   = (const float*)d_in[1];
    const float* ln1w  = (const float*)d_in[2];
    const float* ln1b  = (const float*)d_in[3];
    const float* temp  = (const float*)d_in[4];
    const float* w_kR  = (const float*)d_in[5];
    const float* w_kI  = (const float*)d_in[6];
    const float* w_qR  = (const float*)d_in[7];
    const float* w_qdw = (const float*)d_in[8];
    const float* w_kvI = (const float*)d_in[9];
    const float* w_kvdw= (const float*)d_in[10];
    const float* w_po  = (const float*)d_in[11];
    const float* ln2w  = (const float*)d_in[12];
    const float* ln2b  = (const float*)d_in[13];
    const float* w_ffk = (const float*)d_in[14];
    const float* w_pin = (const float*)d_in[15];
    const float* w_dw  = (const float*)d_in[16];
    const float* w_pout= (const float*)d_in[17];
    float* out = (float*)d_out;

    const size_t MB = 1024 * 1024;
    // Region plan (lifetimes disjoint; peak 192 MiB + smalls):
    float* kv0     = wsf(d_ws, 0);              // [2][384][HW]   -> later g0 part1
    float* kvbuf   = wsf(d_ws, 48 * MB);        // [2][384][HW]   -> later g0 part2
    float* xr      = wsf(d_ws, 96 * MB);        // [2][144][HW]   -> later attnout -> y part1
    float* xi      = wsf(d_ws, 96 * MB + 18874368ULL);  // [2][48][HW]
    float* q0      = wsf(d_ws, 120 * MB);       // [2][192][HW]   -> later y part2
    float* qbuf    = wsf(d_ws, 144 * MB);       // [2][192][HW]   -> later y0
    float* x1      = wsf(d_ws, 168 * MB);       // [2][192][HW]
    float* attnout = wsf(d_ws, 96 * MB);
    float* y0      = wsf(d_ws, 144 * MB);
    float* g0      = wsf(d_ws, 0);              // [2][768][HW] (96 MiB)
    float* ybuf    = wsf(d_ws, 96 * MB);        // [2][384][HW] (48 MiB)
    float* sm      = wsf(d_ws, 192 * MB);       // smalls
    float* kvr  = sm;            // 288
    float* kvi  = sm + 288;      // 96
    float* kvf  = sm + 384;      // 384
    float* invq = sm + 768;      // 384
    float* invk = sm + 1152;     // 384
    float* Smat = sm + 1536;     // 12288
    float* attn = sm + 13824;    // 12288

    // zero the S accumulator (ws is poisoned each call)
    hipMemsetAsync(Smat, 0, 12288 * sizeof(float), stream);

    k_gemv<<<3, 256, 0, stream>>>(k_v, w_kR, w_kI, w_ffk, sm);
    k_ln_mod<<<NPX / 256, 256, 0, stream>>>(x, ln1w, ln1b, kvr, kvi, xr, xi);
    k_conv1x1<144, 128, 2><<<NPX / 128, 256, 0, stream>>>(xr, w_qR, nullptr, q0, 192);
    k_conv1x1<48, 128, 2><<<NPX / 128, 256, 0, stream>>>(xi, w_kvI, nullptr, kv0, 384);
    k_dw<<<(NB * 192 * HW) / 256, 256, 0, stream>>>(q0, w_qdw, qbuf, 192);
    k_dw<<<(NB * 384 * HW) / 256, 256, 0, stream>>>(kv0, w_kvdw, kvbuf, 384);
    k_rownorm<<<768, 256, 0, stream>>>(qbuf, kvbuf, invq, invk);
    k_qk<<<12 * 32, 256, 0, stream>>>(qbuf, kvbuf, Smat);
    k_softmax<<<384, 64, 0, stream>>>(Smat, invq, invk, temp, attn);
    k_av<<<12 * 128, 256, 0, stream>>>(attn, kvbuf, attnout);
    k_conv1x1<192, 64, 2><<<NPX / 64, 256, 0, stream>>>(attnout, w_po, x, x1, 192);
    k_ln_mod<<<NPX / 256, 256, 0, stream>>>(x1, ln2w, ln2b, kvf, nullptr, y0, nullptr);
    k_conv1x1<192, 64, 2><<<NPX / 64, 256, 0, stream>>>(y0, w_pin, nullptr, g0, 768);
    k_dw_gelu<<<(NB * 384 * HW) / 256, 256, 0, stream>>>(g0, w_dw, ybuf);
    k_conv1x1<384, 64, 2><<<NPX / 64, 256, 0, stream>>>(ybuf, w_pout, x1, out, 192);
    k_copy<<<2, 256, 0, stream>>>(k_v, out + (size_t)NB * CDIM * HW);
}

// Round 2
// 535.908 us; speedup vs baseline: 2.6867x; 2.6867x over previous
//
#include <hip/hip_runtime.h>
#include <math.h>

#define HW 16384
#define IMG 128
#define CDIM 192
#define C3 144
#define C4 48
#define NB 2
#define NPX 32768   // NB*HW
#define HEADS 6

typedef unsigned short u16;
typedef __attribute__((ext_vector_type(8))) short bf16x8;
typedef __attribute__((ext_vector_type(4))) float f32x4;

__device__ __forceinline__ float bf2f(u16 u) {
    return __uint_as_float(((unsigned int)u) << 16);
}
__device__ __forceinline__ u16 f2bf(float f) {
    unsigned int x = __float_as_uint(f);
    unsigned int r = x + 0x7fffu + ((x >> 16) & 1u);  // RNE
    return (u16)(r >> 16);
}

static inline float* wsf(void* ws, size_t off) { return (float*)((char*)ws + off); }
static inline u16* wsh(void* ws, size_t off) { return (u16*)((char*)ws + off); }

// ---------------- K0: tiny GEMVs for modulation scales (stored as val+1) ----
__global__ void k_gemv(const float* __restrict__ kvv, const float* __restrict__ wkR,
                       const float* __restrict__ wkI, const float* __restrict__ wffk,
                       float* __restrict__ sm) {
    int t = blockIdx.x * 256 + threadIdx.x;  // 0..767
    if (t < 288) {                       // kvr: [2][144]
        int b = t / 144, o = t % 144;
        const float* v = kvv + b * 256;
        const float* w = wkR + o * 192;
        float s = 0.f;
        for (int j = 0; j < 192; j++) s += v[j] * w[j];
        sm[t] = s + 1.0f;
    } else if (t < 384) {                // kvi: [2][48] at sm+288
        int r = t - 288;
        int b = r / 48, o = r % 48;
        const float* v = kvv + b * 256 + 192;
        const float* w = wkI + o * 64;
        float s = 0.f;
        for (int j = 0; j < 64; j++) s += v[j] * w[j];
        sm[288 + r] = s + 1.0f;
    } else if (t < 768) {                // kvf: [2][192] at sm+384
        int r = t - 384;
        int b = r / 192, o = r % 192;
        const float* v = kvv + b * 256;
        const float* w = wffk + o * 256;
        float s = 0.f;
        for (int j = 0; j < 256; j++) s += v[j] * w[j];
        sm[384 + r] = s + 1.0f;
    }
}

// ---------------- K0b: convert + zero-pad all conv weights to bf16 ----------
// layout: wq[192][160] | wkv[384][64] | wpo[192][192] | wpin[768][192] | wpout[192][384]
__global__ void k_wconv(const float* __restrict__ wqR, const float* __restrict__ wkvI,
                        const float* __restrict__ wpo, const float* __restrict__ wpin,
                        const float* __restrict__ wpout, u16* __restrict__ wb) {
    int t = blockIdx.x * 256 + threadIdx.x;   // grid covers 313344 exactly
    float v;
    if (t < 30720) {
        int o = t / 160, i = t % 160;
        v = (i < 144) ? wqR[o * 144 + i] : 0.f;
    } else if (t < 55296) {
        int r = t - 30720; int o = r / 64, i = r % 64;
        v = (i < 48) ? wkvI[o * 48 + i] : 0.f;
    } else if (t < 92160) {
        v = wpo[t - 55296];
    } else if (t < 239616) {
        v = wpin[t - 92160];
    } else {
        v = wpout[t - 239616];
    }
    wb[t] = f2bf(v);
}

// ---------------- K1: per-pixel channel LayerNorm + modulation (bf16 out) ---
__global__ __launch_bounds__(256) void k_ln_mod(
    const float* __restrict__ x, const float* __restrict__ lnw, const float* __restrict__ lnb,
    const float* __restrict__ sca, const float* __restrict__ scb,
    u16* __restrict__ outA, u16* __restrict__ outB) {
    int g = blockIdx.x * 256 + threadIdx.x;  // < NPX
    int b = g >> 14, p = g & 16383;
    const float* xp = x + (size_t)b * CDIM * HW + p;
    float s = 0.f, s2 = 0.f;
    for (int c = 0; c < CDIM; c++) { float v = xp[(size_t)c * HW]; s += v; s2 += v * v; }
    float mu = s * (1.0f / CDIM);
    float var = s2 * (1.0f / CDIM) - mu * mu;
    float rstd = rsqrtf(var + 1e-5f);
    if (outB) {
        for (int c = 0; c < C3; c++) {
            float v = xp[(size_t)c * HW];
            float xn = (v - mu) * rstd * lnw[c] + lnb[c];
            outA[((size_t)b * C3 + c) * HW + p] = f2bf(xn * sca[b * C3 + c]);
        }
        for (int c = 0; c < C4; c++) {
            float v = xp[(size_t)(C3 + c) * HW];
            float xn = (v - mu) * rstd * lnw[C3 + c] + lnb[C3 + c];
            outB[((size_t)b * C4 + c) * HW + p] = f2bf(xn * scb[b * C4 + c]);
        }
    } else {
        for (int c = 0; c < CDIM; c++) {
            float v = xp[(size_t)c * HW];
            float xn = (v - mu) * rstd * lnw[c] + lnb[c];
            outA[((size_t)b * CDIM + c) * HW + p] = f2bf(xn * sca[b * CDIM + c]);
        }
    }
}

// ---------------- K2: conv1x1 as bf16 MFMA GEMM ------------------------------
// out[b][m][n] = sum_k W[m][k] * X[b][k][n];  M=CO, N=HW (128/tile), K=CIP=NCH*32
// W padded to CIP with zeros, so X reads past CI are garbage*0 (slack required).
// LDS rows are 32 bf16 (64B) with 16B-block XOR swizzle (block ^= row&3).
template <int NCH, bool RESID>
__global__ __launch_bounds__(256) void k_gemm(
    const u16* __restrict__ X, int xrows,
    const u16* __restrict__ Wb,
    const float* __restrict__ resid,
    u16* __restrict__ outb, float* __restrict__ outf, int CO) {
    constexpr int CIP = NCH * 32;
    __shared__ __align__(16) u16 Ws[64 * 32];
    __shared__ __align__(16) u16 Xs[128 * 32];
    const int tid = threadIdx.x;
    const int n0 = blockIdx.x * 128;
    const int m0 = blockIdx.y * 64;
    const int b = blockIdx.z;
    const u16* Xb = X + (size_t)b * xrows * HW + n0;
    const int wave = tid >> 6, lane = tid & 63;
    const int quad = lane >> 4, l16 = lane & 15;
    const int sm = tid >> 2, sk4 = tid & 3;        // W staging
    const int sp = tid >> 1, sih = (tid & 1) * 16; // X staging (transpose)
    f32x4 acc[4][2] = {};
    for (int ch = 0; ch < NCH; ch++) {
        const int k0 = ch * 32;
        if (ch) __syncthreads();
        // stage W chunk [64m][32k]
        {
            const int4 wv = *(const int4*)(Wb + (size_t)(m0 + sm) * CIP + k0 + sk4 * 8);
            *(int4*)&Ws[(sm << 5) + (((sk4 ^ (sm & 3)) & 3) << 3)] = wv;
        }
        // stage X chunk transposed: Xs[n][k], pack k-pairs into b32 writes
        {
            const u16* xc = Xb + (size_t)(k0 + sih) * HW + sp;
#pragma unroll
            for (int jj = 0; jj < 16; jj += 2) {
                unsigned int lo = xc[(size_t)jj * HW];
                unsigned int hi = xc[(size_t)(jj + 1) * HW];
                int i0 = sih + jj;
                *(unsigned int*)&Xs[(sp << 5) + (((i0 >> 3) ^ (sp & 3)) << 3) + (i0 & 7)] =
                    lo | (hi << 16);
            }
        }
        __syncthreads();
        bf16x8 af[4];
#pragma unroll
        for (int mi = 0; mi < 4; mi++) {
            int row = mi * 16 + l16;
            af[mi] = *(const bf16x8*)&Ws[(row << 5) + ((quad ^ (row & 3)) << 3)];
        }
#pragma unroll
        for (int ni = 0; ni < 2; ni++) {
            int nrow = wave * 32 + ni * 16 + l16;
            bf16x8 bfr = *(const bf16x8*)&Xs[(nrow << 5) + ((quad ^ (nrow & 3)) << 3)];
#pragma unroll
            for (int mi = 0; mi < 4; mi++)
                acc[mi][ni] = __builtin_amdgcn_mfma_f32_16x16x32_bf16(af[mi], bfr, acc[mi][ni], 0, 0, 0);
        }
    }
    // epilogue: C/D layout col=lane&15 (=n), row=quad*4+reg (=m)
#pragma unroll
    for (int mi = 0; mi < 4; mi++) {
#pragma unroll
        for (int ni = 0; ni < 2; ni++) {
#pragma unroll
            for (int r = 0; r < 4; r++) {
                int m = m0 + mi * 16 + quad * 4 + r;
                int n = n0 + wave * 32 + ni * 16 + l16;
                size_t idx = ((size_t)b * CO + m) * HW + n;
                float v = acc[mi][ni][r];
                if (RESID) outf[idx] = v + resid[idx];
                else outb[idx] = f2bf(v);
            }
        }
    }
}

// ---------------- K3: depthwise 3x3 (bf16 in, fp32 out) ----------------------
__global__ __launch_bounds__(256) void k_dw(const u16* __restrict__ X,
                                            const float* __restrict__ Wd,
                                            float* __restrict__ out, int Ctot) {
    int g = blockIdx.x * 256 + threadIdx.x;  // < NB*Ctot*HW
    int p = g & 16383;
    int bc = g >> 14;
    int ch = bc % Ctot;
    int py = p >> 7, px = p & 127;
    const u16* xb = X + (size_t)bc * HW;
    const float* w = Wd + ch * 9;
    float s = 0.f;
#pragma unroll
    for (int ky = 0; ky < 3; ky++) {
        int y = py + ky - 1;
        if ((unsigned)y >= (unsigned)IMG) continue;
#pragma unroll
        for (int kx = 0; kx < 3; kx++) {
            int x2 = px + kx - 1;
            if ((unsigned)x2 >= (unsigned)IMG) continue;
            s += w[ky * 3 + kx] * bf2f(xb[y * IMG + x2]);
        }
    }
    out[g] = s;
}

// ---------------- K3b: depthwise 3x3 (pair) + exact GELU gate (bf16) ---------
__global__ __launch_bounds__(256) void k_dw_gelu(const u16* __restrict__ G0,
                                                 const float* __restrict__ Wd,
                                                 u16* __restrict__ out) {
    int g = blockIdx.x * 256 + threadIdx.x;  // < NB*384*HW
    int p = g & 16383;
    int bj = g >> 14;
    int b = bj / 384, j = bj % 384;
    int py = p >> 7, px = p & 127;
    const u16* x1p = G0 + ((size_t)b * 768 + j) * HW;
    const u16* x2p = G0 + ((size_t)b * 768 + 384 + j) * HW;
    const float* w1 = Wd + j * 9;
    const float* w2 = Wd + (384 + j) * 9;
    float s1 = 0.f, s2 = 0.f;
#pragma unroll
    for (int ky = 0; ky < 3; ky++) {
        int y = py + ky - 1;
        if ((unsigned)y >= (unsigned)IMG) continue;
#pragma unroll
        for (int kx = 0; kx < 3; kx++) {
            int x2 = px + kx - 1;
            if ((unsigned)x2 >= (unsigned)IMG) continue;
            int o = y * IMG + x2, k = ky * 3 + kx;
            s1 += w1[k] * bf2f(x1p[o]);
            s2 += w2[k] * bf2f(x2p[o]);
        }
    }
    float a = 0.5f * s1 * (1.0f + erff(s1 * 0.70710678118654752f));
    out[g] = f2bf(a * s2);
}

// ---------------- K4: per-row inverse L2 norms (q rows, k rows) --------------
__global__ __launch_bounds__(256) void k_rownorm(const float* __restrict__ q,
                                                 const float* __restrict__ kvb,
                                                 float* __restrict__ invq,
                                                 float* __restrict__ invk) {
    int r = blockIdx.x;  // 0..767
    const float* ptr;
    if (r < 384) {
        ptr = q + (size_t)r * HW;
    } else {
        int rc = r - 384;
        int b = rc / 192, c2 = rc % 192;
        ptr = kvb + ((size_t)b * 384 + c2) * HW;  // k = first 192 ch of kv
    }
    float s = 0.f;
    for (int i = threadIdx.x; i < HW; i += 256) { float v = ptr[i]; s += v * v; }
    for (int o = 32; o > 0; o >>= 1) s += __shfl_down(s, o, 64);
    __shared__ float red[4];
    int wid = threadIdx.x >> 6, lane = threadIdx.x & 63;
    if (lane == 0) red[wid] = s;
    __syncthreads();
    if (threadIdx.x == 0) {
        float t = red[0] + red[1] + red[2] + red[3];
        float inv = 1.0f / fmaxf(sqrtf(t), 1e-12f);
        if (r < 384) invq[r] = inv; else invk[r - 384] = inv;
    }
}

// ---------------- K5: S = Q * K^T (raw), d-split + atomics -------------------
__global__ __launch_bounds__(256) void k_qk(const float* __restrict__ q,
                                            const float* __restrict__ kvb,
                                            float* __restrict__ S) {
    __shared__ float Qs[32 * 64];
    __shared__ float Ks[32 * 65];
    int bh = blockIdx.x >> 5;       // 0..11
    int ds = blockIdx.x & 31;       // 0..31
    int b = bh / HEADS, h = bh % HEADS;
    const float* qb = q + ((size_t)b * CDIM + h * 32) * HW;
    const float* kb = kvb + ((size_t)b * 384 + h * 32) * HW;
    int tid = threadIdx.x;
    int c0 = tid >> 5;   // 0..7
    int e = tid & 31;
    float acc[4] = {0.f, 0.f, 0.f, 0.f};
    int dbeg = ds * 512;
    for (int d0 = dbeg; d0 < dbeg + 512; d0 += 64) {
        for (int idx = tid; idx < 2048; idx += 256) {
            int r = idx >> 6, dd = idx & 63;
            Qs[r * 64 + dd] = qb[(size_t)r * HW + d0 + dd];
            Ks[r * 65 + dd] = kb[(size_t)r * HW + d0 + dd];
        }
        __syncthreads();
        for (int dd = 0; dd < 64; dd++) {
            float kvv = Ks[e * 65 + dd];
#pragma unroll
            for (int k2 = 0; k2 < 4; k2++) acc[k2] += Qs[(c0 + 8 * k2) * 64 + dd] * kvv;
        }
        __syncthreads();
    }
    float* Sb = S + bh * 1024;
#pragma unroll
    for (int k2 = 0; k2 < 4; k2++) atomicAdd(&Sb[(c0 + 8 * k2) * 32 + e], acc[k2]);
}

// ---------------- K6: normalize + temp + softmax over 32 ---------------------
__global__ void k_softmax(const float* __restrict__ S, const float* __restrict__ invq,
                          const float* __restrict__ invk, const float* __restrict__ temp,
                          float* __restrict__ attn) {
    int row = blockIdx.x;           // 0..383
    int bh = row >> 5, c2 = row & 31;
    int b = bh / HEADS, h = bh % HEADS;
    int e = threadIdx.x;            // 64 threads, active e<32
    float l = -1e30f;
    if (e < 32)
        l = S[bh * 1024 + c2 * 32 + e] * invq[b * CDIM + h * 32 + c2] *
            invk[b * CDIM + h * 32 + e] * temp[h];
    float m = l;
    for (int o = 32; o > 0; o >>= 1) m = fmaxf(m, __shfl_xor(m, o, 64));
    float ev = (e < 32) ? expf(l - m) : 0.f;
    float ssum = ev;
    for (int o = 32; o > 0; o >>= 1) ssum += __shfl_xor(ssum, o, 64);
    if (e < 32) attn[bh * 1024 + c2 * 32 + e] = ev / ssum;
}

// ---------------- K7: out = attn @ V (bf16 out) ------------------------------
__global__ __launch_bounds__(256) void k_av(const float* __restrict__ attn,
                                            const float* __restrict__ kvb,
                                            u16* __restrict__ out) {
    __shared__ float As[1024];
    __shared__ float Vs[32 * 128];
    int bh = blockIdx.x >> 7;       // 0..11
    int pt = blockIdx.x & 127;      // pixel tile
    int b = bh / HEADS, h = bh % HEADS;
    int pl0 = pt * 128;
    int tid = threadIdx.x;
    for (int idx = tid; idx < 1024; idx += 256) As[idx] = attn[bh * 1024 + idx];
    const float* vb = kvb + ((size_t)b * 384 + 192 + h * 32) * HW + pl0;
    for (int idx = tid; idx < 4096; idx += 256) {
        int e2 = idx >> 7, pp = idx & 127;
        Vs[idx] = vb[(size_t)e2 * HW + pp];
    }
    __syncthreads();
    int pp = tid & 127;
    int cb = tid >> 7;  // 0..1
    u16* ob = out + ((size_t)b * CDIM + h * 32) * HW + pl0;
    for (int k2 = 0; k2 < 16; k2++) {
        int c2 = cb * 16 + k2;
        float s = 0.f;
#pragma unroll 8
        for (int e2 = 0; e2 < 32; e2++) s += As[c2 * 32 + e2] * Vs[e2 * 128 + pp];
        ob[(size_t)c2 * HW + pp] = f2bf(s);
    }
}

// ---------------- K8: pass k_v through to output tail ------------------------
__global__ void k_copy(const float* __restrict__ kvv, float* __restrict__ out) {
    int t = blockIdx.x * 256 + threadIdx.x;
    if (t < 512) out[t] = kvv[t];
}

extern "C" void kernel_launch(void* const* d_in, const int* in_sizes, int n_in,
                              void* d_out, int out_size, void* d_ws, size_t ws_size,
                              hipStream_t stream) {
    const float* x     = (const float*)d_in[0];
    const float* k_v   = (const float*)d_in[1];
    const float* ln1w  = (const float*)d_in[2];
    const float* ln1b  = (const float*)d_in[3];
    const float* temp  = (const float*)d_in[4];
    const float* w_kR  = (const float*)d_in[5];
    const float* w_kI  = (const float*)d_in[6];
    const float* w_qR  = (const float*)d_in[7];
    const float* w_qdw = (const float*)d_in[8];
    const float* w_kvI = (const float*)d_in[9];
    const float* w_kvdw= (const float*)d_in[10];
    const float* w_po  = (const float*)d_in[11];
    const float* ln2w  = (const float*)d_in[12];
    const float* ln2b  = (const float*)d_in[13];
    const float* w_ffk = (const float*)d_in[14];
    const float* w_pin = (const float*)d_in[15];
    const float* w_dw  = (const float*)d_in[16];
    const float* w_pout= (const float*)d_in[17];
    float* out = (float*)d_out;

    const size_t MiB = 1048576ULL;
    // Region plan (disjoint lifetimes; peak ~133 MiB):
    float* kvbuf   = wsf(d_ws, 0);          // [2][384][HW] f32 (steps 4-5) / g0 bf16 (8-9)
    u16*   g0b     = wsh(d_ws, 0);
    u16*   kv0b    = wsh(d_ws, 48 * MiB);   // [2][384][HW] bf16 (3-4)
    float* x1      = wsf(d_ws, 48 * MiB);   // [2][192][HW] f32 (6-10), over kv0+qbuf
    float* qbuf    = wsf(d_ws, 72 * MiB);   // [2][192][HW] f32 (4-5)
    u16*   q0b     = wsh(d_ws, 96 * MiB);   // [2][192][HW] bf16 (3-4) / attnout (5-6) / y0 (7-8)
    u16*   attnoutb= wsh(d_ws, 96 * MiB);
    u16*   y0b     = wsh(d_ws, 96 * MiB);
    u16*   xrb     = wsh(d_ws, 108 * MiB);  // [2][144][HW] bf16 + K-pad slack (2-3)
    u16*   xib     = wsh(d_ws, 118 * MiB);  // [2][48][HW] bf16 + slack (2-3)
    u16*   ybufb   = wsh(d_ws, 108 * MiB);  // [2][384][HW] bf16 (9-10), over xr+xi
    u16*   wb      = wsh(d_ws, 132 * MiB);  // bf16 weights, 627 KB
    float* sm      = wsf(d_ws, 133 * MiB);  // smalls
    u16* wq   = wb;            // [192][160]
    u16* wkv  = wb + 30720;    // [384][64]
    u16* wpo  = wb + 55296;    // [192][192]
    u16* wpin = wb + 92160;    // [768][192]
    u16* wpout= wb + 239616;   // [192][384]
    float* kvr  = sm;            // 288
    float* kvi  = sm + 288;      // 96
    float* kvf  = sm + 384;      // 384
    float* invq = sm + 768;      // 384
    float* invk = sm + 1152;     // 384
    float* Smat = sm + 1536;     // 12288
    float* attn = sm + 13824;    // 12288

    hipMemsetAsync(Smat, 0, 12288 * sizeof(float), stream);

    k_wconv<<<1224, 256, 0, stream>>>(w_qR, w_kvI, w_po, w_pin, w_pout, wb);
    k_gemv<<<3, 256, 0, stream>>>(k_v, w_kR, w_kI, w_ffk, sm);
    k_ln_mod<<<NPX / 256, 256, 0, stream>>>(x, ln1w, ln1b, kvr, kvi, xrb, xib);
    k_gemm<5, false><<<dim3(128, 3, 2), 256, 0, stream>>>(xrb, 144, wq, nullptr, q0b, nullptr, 192);
    k_gemm<2, false><<<dim3(128, 6, 2), 256, 0, stream>>>(xib, 48, wkv, nullptr, kv0b, nullptr, 384);
    k_dw<<<(NB * 192 * HW) / 256, 256, 0, stream>>>(q0b, w_qdw, qbuf, 192);
    k_dw<<<(NB * 384 * HW) / 256, 256, 0, stream>>>(kv0b, w_kvdw, kvbuf, 384);
    k_rownorm<<<768, 256, 0, stream>>>(qbuf, kvbuf, invq, invk);
    k_qk<<<12 * 32, 256, 0, stream>>>(qbuf, kvbuf, Smat);
    k_softmax<<<384, 64, 0, stream>>>(Smat, invq, invk, temp, attn);
    k_av<<<12 * 128, 256, 0, stream>>>(attn, kvbuf, attnoutb);
    k_gemm<6, true><<<dim3(128, 3, 2), 256, 0, stream>>>(attnoutb, 192, wpo, x, nullptr, x1, 192);
    k_ln_mod<<<NPX / 256, 256, 0, stream>>>(x1, ln2w, ln2b, kvf, nullptr, y0b, nullptr);
    k_gemm<6, false><<<dim3(128, 12, 2), 256, 0, stream>>>(y0b, 192, wpin, nullptr, g0b, nullptr, 768);
    k_dw_gelu<<<(NB * 384 * HW) / 256, 256, 0, stream>>>(g0b, w_dw, ybufb);
    k_gemm<12, true><<<dim3(128, 3, 2), 256, 0, stream>>>(ybufb, 384, wpout, x1, nullptr, out, 192);
    k_copy<<<2, 256, 0, stream>>>(k_v, out + (size_t)NB * CDIM * HW);
}

// Round 3
// 300.928 us; speedup vs baseline: 4.7845x; 1.7808x over previous
//
#include <hip/hip_runtime.h>
#include <math.h>

#define HW 16384
#define IMG 128
#define CDIM 192
#define C3 144
#define C4 48
#define NB 2
#define NPX 32768   // NB*HW
#define HEADS 6

typedef unsigned short u16;
typedef unsigned int u32;
typedef __attribute__((ext_vector_type(8))) short bf16x8;
typedef __attribute__((ext_vector_type(4))) float f32x4;

__device__ __forceinline__ float bf2f(u16 u) {
    return __uint_as_float(((unsigned int)u) << 16);
}
__device__ __forceinline__ u16 f2bf(float f) {
    unsigned int x = __float_as_uint(f);
    unsigned int r = x + 0x7fffu + ((x >> 16) & 1u);  // RNE
    return (u16)(r >> 16);
}

static inline float* wsf(void* ws, size_t off) { return (float*)((char*)ws + off); }
static inline u16* wsh(void* ws, size_t off) { return (u16*)((char*)ws + off); }

// ---------------- K0: tiny GEMVs for modulation scales (stored as val+1) ----
__global__ void k_gemv(const float* __restrict__ kvv, const float* __restrict__ wkR,
                       const float* __restrict__ wkI, const float* __restrict__ wffk,
                       float* __restrict__ sm) {
    int t = blockIdx.x * 256 + threadIdx.x;  // 0..767
    if (t < 288) {                       // kvr: [2][144]
        int b = t / 144, o = t % 144;
        const float* v = kvv + b * 256;
        const float* w = wkR + o * 192;
        float s = 0.f;
        for (int j = 0; j < 192; j++) s += v[j] * w[j];
        sm[t] = s + 1.0f;
    } else if (t < 384) {                // kvi: [2][48] at sm+288
        int r = t - 288;
        int b = r / 48, o = r % 48;
        const float* v = kvv + b * 256 + 192;
        const float* w = wkI + o * 64;
        float s = 0.f;
        for (int j = 0; j < 64; j++) s += v[j] * w[j];
        sm[288 + r] = s + 1.0f;
    } else if (t < 768) {                // kvf: [2][192] at sm+384
        int r = t - 384;
        int b = r / 192, o = r % 192;
        const float* v = kvv + b * 256;
        const float* w = wffk + o * 256;
        float s = 0.f;
        for (int j = 0; j < 256; j++) s += v[j] * w[j];
        sm[384 + r] = s + 1.0f;
    }
}

// ---------------- K0b: convert + zero-pad all conv weights to bf16 ----------
// layout: wq[192][160] | wkv[384][64] | wpo[192][192] | wpin[768][192] | wpout[192][384]
__global__ void k_wconv(const float* __restrict__ wqR, const float* __restrict__ wkvI,
                        const float* __restrict__ wpo, const float* __restrict__ wpin,
                        const float* __restrict__ wpout, u16* __restrict__ wb) {
    int t = blockIdx.x * 256 + threadIdx.x;   // grid covers 313344 exactly
    float v;
    if (t < 30720) {
        int o = t / 160, i = t % 160;
        v = (i < 144) ? wqR[o * 144 + i] : 0.f;
    } else if (t < 55296) {
        int r = t - 30720; int o = r / 64, i = r % 64;
        v = (i < 48) ? wkvI[o * 48 + i] : 0.f;
    } else if (t < 92160) {
        v = wpo[t - 55296];
    } else if (t < 239616) {
        v = wpin[t - 92160];
    } else {
        v = wpout[t - 239616];
    }
    wb[t] = f2bf(v);
}

// ---------------- K1: per-pixel channel LayerNorm + modulation (bf16 out) ---
__global__ __launch_bounds__(256) void k_ln_mod(
    const float* __restrict__ x, const float* __restrict__ lnw, const float* __restrict__ lnb,
    const float* __restrict__ sca, const float* __restrict__ scb,
    u16* __restrict__ outA, u16* __restrict__ outB) {
    int g = blockIdx.x * 256 + threadIdx.x;  // < NPX
    int b = g >> 14, p = g & 16383;
    const float* xp = x + (size_t)b * CDIM * HW + p;
    float s = 0.f, s2 = 0.f;
    for (int c = 0; c < CDIM; c++) { float v = xp[(size_t)c * HW]; s += v; s2 += v * v; }
    float mu = s * (1.0f / CDIM);
    float var = s2 * (1.0f / CDIM) - mu * mu;
    float rstd = rsqrtf(var + 1e-5f);
    if (outB) {
        for (int c = 0; c < C3; c++) {
            float v = xp[(size_t)c * HW];
            float xn = (v - mu) * rstd * lnw[c] + lnb[c];
            outA[((size_t)b * C3 + c) * HW + p] = f2bf(xn * sca[b * C3 + c]);
        }
        for (int c = 0; c < C4; c++) {
            float v = xp[(size_t)(C3 + c) * HW];
            float xn = (v - mu) * rstd * lnw[C3 + c] + lnb[C3 + c];
            outB[((size_t)b * C4 + c) * HW + p] = f2bf(xn * scb[b * C4 + c]);
        }
    } else {
        for (int c = 0; c < CDIM; c++) {
            float v = xp[(size_t)c * HW];
            float xn = (v - mu) * rstd * lnw[c] + lnb[c];
            outA[((size_t)b * CDIM + c) * HW + p] = f2bf(xn * sca[b * CDIM + c]);
        }
    }
}

// ---------------- K2: conv1x1 as bf16 MFMA GEMM ------------------------------
// out[b][m][n] = sum_k W[m][k] * X[b][k][n];  M=CO, N=HW(128/tile), K=NCH*32.
// W zero-padded to K, so X reads past CI are garbage*0 (slack required).
// Xs layout: [k][n] rows of 130 u16 -> B-frag scalar reads hit (k + n/2)%32
// banks: quads offset by 8 banks, 2 lanes/bank -> conflict-free.
template <int NCH, bool RESID>
__global__ __launch_bounds__(256) void k_gemm(
    const u16* __restrict__ X, int xrows,
    const u16* __restrict__ Wb,
    const float* __restrict__ resid,
    u16* __restrict__ outb, float* __restrict__ outf, int CO) {
    constexpr int CIP = NCH * 32;
    __shared__ __align__(16) u16 Ws[64 * 32];
    __shared__ __align__(16) u16 Xs[32 * 130];
    const int tid = threadIdx.x;
    const int n0 = blockIdx.x * 128;
    const int m0 = blockIdx.y * 64;
    const int b = blockIdx.z;
    const u16* Xb = X + (size_t)b * xrows * HW + n0;
    const int wave = tid >> 6, lane = tid & 63;
    const int quad = lane >> 4, l16 = lane & 15;
    const int smr = tid >> 2, sk4 = tid & 3;       // W staging
    const int skr = tid >> 3, sc0 = (tid & 7) * 16; // X staging
    f32x4 acc[4][2] = {};
    for (int ch = 0; ch < NCH; ch++) {
        const int k0 = ch * 32;
        if (ch) __syncthreads();
        // stage W chunk [64m][32k] (swizzled, b128-friendly)
        {
            const int4 wv = *(const int4*)(Wb + (size_t)(m0 + smr) * CIP + k0 + sk4 * 8);
            *(int4*)&Ws[(smr << 5) + (((sk4 ^ (smr & 3)) & 3) << 3)] = wv;
        }
        // stage X chunk [32k][128n] coalesced, row stride 130
        {
            const u16* xc = Xb + (size_t)(k0 + skr) * HW + sc0;
            int4 r0 = *(const int4*)xc;
            int4 r1 = *(const int4*)(xc + 8);
            u32* dst = (u32*)&Xs[skr * 130 + sc0];
#pragma unroll
            for (int i = 0; i < 4; i++) dst[i] = ((const u32*)&r0)[i];
#pragma unroll
            for (int i = 0; i < 4; i++) dst[4 + i] = ((const u32*)&r1)[i];
        }
        __syncthreads();
        bf16x8 af[4];
#pragma unroll
        for (int mi = 0; mi < 4; mi++) {
            int row = mi * 16 + l16;
            af[mi] = *(const bf16x8*)&Ws[(row << 5) + ((quad ^ (row & 3)) << 3)];
        }
#pragma unroll
        for (int ni = 0; ni < 2; ni++) {
            int n = wave * 32 + ni * 16 + l16;
            bf16x8 bfr;
#pragma unroll
            for (int j = 0; j < 8; j++) bfr[j] = (short)Xs[(quad * 8 + j) * 130 + n];
#pragma unroll
            for (int mi = 0; mi < 4; mi++)
                acc[mi][ni] = __builtin_amdgcn_mfma_f32_16x16x32_bf16(af[mi], bfr, acc[mi][ni], 0, 0, 0);
        }
    }
    // epilogue: C/D layout col=lane&15 (=n), row=quad*4+reg (=m)
#pragma unroll
    for (int mi = 0; mi < 4; mi++) {
#pragma unroll
        for (int ni = 0; ni < 2; ni++) {
#pragma unroll
            for (int r = 0; r < 4; r++) {
                int m = m0 + mi * 16 + quad * 4 + r;
                int n = n0 + wave * 32 + ni * 16 + l16;
                size_t idx = ((size_t)b * CO + m) * HW + n;
                float v = acc[mi][ni][r];
                if (RESID) outf[idx] = v + resid[idx];
                else outb[idx] = f2bf(v);
            }
        }
    }
}

// ---------------- K3: depthwise 3x3, LDS-tiled, bf16 in/out, fused sumsq -----
__global__ __launch_bounds__(256) void k_dw2(const u16* __restrict__ X,
                                             const float* __restrict__ Wd,
                                             u16* __restrict__ out, int C, int sqCh,
                                             float* __restrict__ sqacc) {
    __shared__ float In[34 * 132];
    __shared__ float red[4];
    int bc = blockIdx.x >> 2, rt = blockIdx.x & 3;
    int b = bc / C, ch = bc % C;
    const u16* xb = X + (size_t)bc * HW;
    int t = threadIdx.x;
    int c0 = (t & 7) * 16;
    for (int r = t >> 3; r < 34; r += 32) {
        int y = rt * 32 - 1 + r;
        float* dst = &In[r * 132 + 1 + c0];
        if ((unsigned)y < 128u) {
            const u16* src = xb + y * 128 + c0;
            int4 r0 = *(const int4*)src;
            int4 r1 = *(const int4*)(src + 8);
            const u16* p0 = (const u16*)&r0;
            const u16* p1 = (const u16*)&r1;
#pragma unroll
            for (int i = 0; i < 8; i++) dst[i] = bf2f(p0[i]);
#pragma unroll
            for (int i = 0; i < 8; i++) dst[8 + i] = bf2f(p1[i]);
        } else {
#pragma unroll
            for (int i = 0; i < 16; i++) dst[i] = 0.f;
        }
    }
    if (t < 34) { In[t * 132] = 0.f; In[t * 132 + 129] = 0.f; }
    __syncthreads();
    const float* w = Wd + ch * 9;
    float w00 = w[0], w01 = w[1], w02 = w[2], w10 = w[3], w11 = w[4],
          w12 = w[5], w20 = w[6], w21 = w[7], w22 = w[8];
    int x = t & 127, rg = t >> 7;
    int base = rg * 16;
    float A2 = 0.f, A1 = 0.f, B1 = 0.f, ssq = 0.f;
    u16* ob = out + (size_t)bc * HW + (rt * 32 + base) * 128 + x;
#pragma unroll
    for (int r = 0; r < 18; r++) {
        const float* row = &In[(base + r) * 132 + x];
        float v0 = row[0], v1 = row[1], v2 = row[2];
        float h0 = w00 * v0 + w01 * v1 + w02 * v2;
        float h1 = w10 * v0 + w11 * v1 + w12 * v2;
        float h2 = w20 * v0 + w21 * v1 + w22 * v2;
        if (r >= 2) {
            float val = A2 + B1 + h2;
            ob[(size_t)(r - 2) * 128] = f2bf(val);
            ssq += val * val;
        }
        A2 = A1; A1 = h0; B1 = h1;
    }
    if (ch < sqCh) {   // block-uniform
        for (int o = 32; o > 0; o >>= 1) ssq += __shfl_down(ssq, o, 64);
        int wid = t >> 6, lane = t & 63;
        if (lane == 0) red[wid] = ssq;
        __syncthreads();
        if (t == 0) atomicAdd(&sqacc[b * 192 + ch], red[0] + red[1] + red[2] + red[3]);
    }
}

// ---------------- K3b: depthwise 3x3 pair + exact GELU gate, LDS-tiled -------
__global__ __launch_bounds__(256) void k_dw_gelu2(const u16* __restrict__ G0,
                                                  const float* __restrict__ Wd,
                                                  u16* __restrict__ out) {
    __shared__ float In[2 * 34 * 132];
    int bc = blockIdx.x >> 2, rt = blockIdx.x & 3;
    int b = bc / 384, j = bc % 384;
    int t = threadIdx.x;
    int c0 = (t & 7) * 16;
    for (int pl = 0; pl < 2; pl++) {
        const u16* xb = G0 + ((size_t)b * 768 + pl * 384 + j) * HW;
        float* pla = &In[pl * 34 * 132];
        for (int r = t >> 3; r < 34; r += 32) {
            int y = rt * 32 - 1 + r;
            float* dst = &pla[r * 132 + 1 + c0];
            if ((unsigned)y < 128u) {
                const u16* src = xb + y * 128 + c0;
                int4 r0 = *(const int4*)src;
                int4 r1 = *(const int4*)(src + 8);
                const u16* p0 = (const u16*)&r0;
                const u16* p1 = (const u16*)&r1;
#pragma unroll
                for (int i = 0; i < 8; i++) dst[i] = bf2f(p0[i]);
#pragma unroll
                for (int i = 0; i < 8; i++) dst[8 + i] = bf2f(p1[i]);
            } else {
#pragma unroll
                for (int i = 0; i < 16; i++) dst[i] = 0.f;
            }
        }
        if (t < 34) { pla[t * 132] = 0.f; pla[t * 132 + 129] = 0.f; }
    }
    __syncthreads();
    const float* w1 = Wd + j * 9;
    const float* w2 = Wd + (384 + j) * 9;
    float a00 = w1[0], a01 = w1[1], a02 = w1[2], a10 = w1[3], a11 = w1[4],
          a12 = w1[5], a20 = w1[6], a21 = w1[7], a22 = w1[8];
    float b00 = w2[0], b01 = w2[1], b02 = w2[2], b10 = w2[3], b11 = w2[4],
          b12 = w2[5], b20 = w2[6], b21 = w2[7], b22 = w2[8];
    int x = t & 127, rg = t >> 7;
    int base = rg * 16;
    float A2a = 0.f, A1a = 0.f, B1a = 0.f;
    float A2b = 0.f, A1b = 0.f, B1b = 0.f;
    u16* ob = out + ((size_t)b * 384 + j) * HW + (rt * 32 + base) * 128 + x;
#pragma unroll
    for (int r = 0; r < 18; r++) {
        const float* r1p = &In[(base + r) * 132 + x];
        const float* r2p = r1p + 34 * 132;
        float u0 = r1p[0], u1 = r1p[1], u2 = r1p[2];
        float v0 = r2p[0], v1 = r2p[1], v2 = r2p[2];
        float h0a = a00 * u0 + a01 * u1 + a02 * u2;
        float h1a = a10 * u0 + a11 * u1 + a12 * u2;
        float h2a = a20 * u0 + a21 * u1 + a22 * u2;
        float h0b = b00 * v0 + b01 * v1 + b02 * v2;
        float h1b = b10 * v0 + b11 * v1 + b12 * v2;
        float h2b = b20 * v0 + b21 * v1 + b22 * v2;
        if (r >= 2) {
            float s1 = A2a + B1a + h2a;
            float s2 = A2b + B1b + h2b;
            float g = 0.5f * s1 * (1.0f + erff(s1 * 0.70710678118654752f));
            ob[(size_t)(r - 2) * 128] = f2bf(g * s2);
        }
        A2a = A1a; A1a = h0a; B1a = h1a;
        A2b = A1b; A1b = h0b; B1b = h1b;
    }
}

// ---------------- K5: S = Q*K^T via MFMA straight from global, d-split -------
__global__ __launch_bounds__(256) void k_qk(const u16* __restrict__ qb_,
                                            const u16* __restrict__ kb_,
                                            float* __restrict__ S) {
    int bx = blockIdx.x;            // bh*64 + ds
    int bh = bx >> 6, ds = bx & 63;
    int b = bh / HEADS, h = bh % HEADS;
    int tid = threadIdx.x;
    int wave = tid >> 6, lane = tid & 63;
    int quad = lane >> 4, l16 = lane & 15;
    int tm = wave >> 1, tn = wave & 1;
    const u16* qrow = qb_ + ((size_t)(b * 192 + h * 32 + tm * 16 + l16)) * HW + ds * 256 + quad * 8;
    const u16* krow = kb_ + ((size_t)(b * 384 + h * 32 + tn * 16 + l16)) * HW + ds * 256 + quad * 8;
    f32x4 acc = {};
#pragma unroll
    for (int ch = 0; ch < 8; ch++) {
        bf16x8 a = *(const bf16x8*)(qrow + ch * 32);
        bf16x8 k8 = *(const bf16x8*)(krow + ch * 32);
        acc = __builtin_amdgcn_mfma_f32_16x16x32_bf16(a, k8, acc, 0, 0, 0);
    }
    float* Sb = S + bh * 1024;
#pragma unroll
    for (int r = 0; r < 4; r++)
        atomicAdd(&Sb[(tm * 16 + quad * 4 + r) * 32 + tn * 16 + l16], acc[r]);
}

// ---------------- K6: normalize + temp + softmax over 32, bf16 out -----------
__global__ void k_softmax(const float* __restrict__ S, const float* __restrict__ sqq,
                          const float* __restrict__ sqk, const float* __restrict__ temp,
                          u16* __restrict__ attnb) {
    int row = blockIdx.x;           // 0..383
    int bh = row >> 5, c2 = row & 31;
    int b = bh / HEADS, h = bh % HEADS;
    int e = threadIdx.x;            // 64 threads, active e<32
    float l = -1e30f;
    if (e < 32) {
        float invq = 1.0f / fmaxf(sqrtf(sqq[b * 192 + h * 32 + c2]), 1e-12f);
        float invk = 1.0f / fmaxf(sqrtf(sqk[b * 192 + h * 32 + e]), 1e-12f);
        l = S[bh * 1024 + c2 * 32 + e] * invq * invk * temp[h];
    }
    float m = l;
    for (int o = 32; o > 0; o >>= 1) m = fmaxf(m, __shfl_xor(m, o, 64));
    float ev = (e < 32) ? expf(l - m) : 0.f;
    float ssum = ev;
    for (int o = 32; o > 0; o >>= 1) ssum += __shfl_xor(ssum, o, 64);
    if (e < 32) attnb[bh * 1024 + c2 * 32 + e] = f2bf(ev / ssum);
}

// ---------------- K7: out = attn @ V via MFMA, V staged [e][p] in LDS --------
__global__ __launch_bounds__(256) void k_av(const u16* __restrict__ attnb,
                                            const u16* __restrict__ kvb,
                                            u16* __restrict__ out) {
    __shared__ __align__(16) u16 Vs[32 * 130];
    int bh = blockIdx.x >> 7;       // 12
    int pt = blockIdx.x & 127;
    int b = bh / HEADS, h = bh % HEADS;
    int p0 = pt * 128;
    int t = threadIdx.x;
    {   // stage V tile [32e][128p]
        int e = t >> 3, c0 = (t & 7) * 16;
        const u16* src = kvb + ((size_t)(b * 384 + 192 + h * 32 + e)) * HW + p0 + c0;
        int4 r0 = *(const int4*)src;
        int4 r1 = *(const int4*)(src + 8);
        u32* dst = (u32*)&Vs[e * 130 + c0];
#pragma unroll
        for (int i = 0; i < 4; i++) dst[i] = ((const u32*)&r0)[i];
#pragma unroll
        for (int i = 0; i < 4; i++) dst[4 + i] = ((const u32*)&r1)[i];
    }
    __syncthreads();
    int wave = t >> 6, lane = t & 63;
    int quad = lane >> 4, l16 = lane & 15;
    f32x4 acc[2][2] = {};
    bf16x8 af[2];
#pragma unroll
    for (int tm = 0; tm < 2; tm++)
        af[tm] = *(const bf16x8*)(attnb + bh * 1024 + (tm * 16 + l16) * 32 + quad * 8);
#pragma unroll
    for (int nt = 0; nt < 2; nt++) {
        int n = wave * 32 + nt * 16 + l16;
        bf16x8 bfr;
#pragma unroll
        for (int j = 0; j < 8; j++) bfr[j] = (short)Vs[(quad * 8 + j) * 130 + n];
#pragma unroll
        for (int tm = 0; tm < 2; tm++)
            acc[tm][nt] = __builtin_amdgcn_mfma_f32_16x16x32_bf16(af[tm], bfr, acc[tm][nt], 0, 0, 0);
    }
#pragma unroll
    for (int tm = 0; tm < 2; tm++)
#pragma unroll
        for (int nt = 0; nt < 2; nt++)
#pragma unroll
            for (int r = 0; r < 4; r++) {
                int c = h * 32 + tm * 16 + quad * 4 + r;
                int p = p0 + wave * 32 + nt * 16 + l16;
                out[((size_t)b * 192 + c) * HW + p] = f2bf(acc[tm][nt][r]);
            }
}

// ---------------- K8: pass k_v through to output tail ------------------------
__global__ void k_copy(const float* __restrict__ kvv, float* __restrict__ out) {
    int t = blockIdx.x * 256 + threadIdx.x;
    if (t < 512) out[t] = kvv[t];
}

extern "C" void kernel_launch(void* const* d_in, const int* in_sizes, int n_in,
                              void* d_out, int out_size, void* d_ws, size_t ws_size,
                              hipStream_t stream) {
    const float* x     = (const float*)d_in[0];
    const float* k_v   = (const float*)d_in[1];
    const float* ln1w  = (const float*)d_in[2];
    const float* ln1b  = (const float*)d_in[3];
    const float* temp  = (const float*)d_in[4];
    const float* w_kR  = (const float*)d_in[5];
    const float* w_kI  = (const float*)d_in[6];
    const float* w_qR  = (const float*)d_in[7];
    const float* w_qdw = (const float*)d_in[8];
    const float* w_kvI = (const float*)d_in[9];
    const float* w_kvdw= (const float*)d_in[10];
    const float* w_po  = (const float*)d_in[11];
    const float* ln2w  = (const float*)d_in[12];
    const float* ln2b  = (const float*)d_in[13];
    const float* w_ffk = (const float*)d_in[14];
    const float* w_pin = (const float*)d_in[15];
    const float* w_dw  = (const float*)d_in[16];
    const float* w_pout= (const float*)d_in[17];
    float* out = (float*)d_out;

    const size_t MiB = 1048576ULL;
    // Region plan (disjoint lifetimes; peak ~184 MiB):
    u16*   q0b     = wsh(d_ws, 0);          // [2][192] bf16 (3-5) / attnout (av-po) / y0 (ln2-pin)
    u16*   attnoutb= wsh(d_ws, 0);
    u16*   y0b     = wsh(d_ws, 0);
    u16*   kv0b    = wsh(d_ws, 12 * MiB);   // [2][384] bf16 (3-6)
    u16*   ybufb   = wsh(d_ws, 12 * MiB);   // [2][384] bf16 (gelu-pout)
    float* x1      = wsf(d_ws, 36 * MiB);   // [2][192] f32 (po-pout)
    u16*   qbuf_b  = wsh(d_ws, 84 * MiB);   // [2][192] bf16 (dwq-qk)
    u16*   kvbuf_b = wsh(d_ws, 96 * MiB);   // [2][384] bf16 (dwkv-av)
    u16*   xrb     = wsh(d_ws, 120 * MiB);  // [2][144] bf16 + 1MiB K-pad slack
    u16*   xib     = wsh(d_ws, 130 * MiB);  // [2][48] bf16 + 1MiB slack
    u16*   g0b     = wsh(d_ws, 134 * MiB);  // [2][768] bf16 (pin-gelu)
    u16*   wb      = wsh(d_ws, 182 * MiB);  // bf16 weights, 627 KB
    float* sm      = wsf(d_ws, 183 * MiB);  // smalls
    u16* wq   = wb;            // [192][160]
    u16* wkv  = wb + 30720;    // [384][64]
    u16* wpo  = wb + 55296;    // [192][192]
    u16* wpin = wb + 92160;    // [768][192]
    u16* wpout= wb + 239616;   // [192][384]
    float* kvr  = sm;             // 288
    float* kvi  = sm + 288;       // 96
    float* kvf  = sm + 384;       // 384
    float* sqq  = sm + 768;       // 384
    float* sqk  = sm + 1152;      // 384
    float* Smat = sm + 1536;      // 12288
    u16*   attnb= (u16*)(sm + 13824);  // 12288 bf16

    // zero sumsq accumulators + S (ws is poisoned each call)
    hipMemsetAsync(sm + 768, 0, (768 + 12288) * sizeof(float), stream);

    k_wconv<<<1224, 256, 0, stream>>>(w_qR, w_kvI, w_po, w_pin, w_pout, wb);
    k_gemv<<<3, 256, 0, stream>>>(k_v, w_kR, w_kI, w_ffk, sm);
    k_ln_mod<<<NPX / 256, 256, 0, stream>>>(x, ln1w, ln1b, kvr, kvi, xrb, xib);
    k_gemm<5, false><<<dim3(128, 3, 2), 256, 0, stream>>>(xrb, 144, wq, nullptr, q0b, nullptr, 192);
    k_gemm<2, false><<<dim3(128, 6, 2), 256, 0, stream>>>(xib, 48, wkv, nullptr, kv0b, nullptr, 384);
    k_dw2<<<NB * 192 * 4, 256, 0, stream>>>(q0b, w_qdw, qbuf_b, 192, 192, sqq);
    k_dw2<<<NB * 384 * 4, 256, 0, stream>>>(kv0b, w_kvdw, kvbuf_b, 384, 192, sqk);
    k_qk<<<12 * 64, 256, 0, stream>>>(qbuf_b, kvbuf_b, Smat);
    k_softmax<<<384, 64, 0, stream>>>(Smat, sqq, sqk, temp, attnb);
    k_av<<<12 * 128, 256, 0, stream>>>(attnb, kvbuf_b, attnoutb);
    k_gemm<6, true><<<dim3(128, 3, 2), 256, 0, stream>>>(attnoutb, 192, wpo, x, nullptr, x1, 192);
    k_ln_mod<<<NPX / 256, 256, 0, stream>>>(x1, ln2w, ln2b, kvf, nullptr, y0b, nullptr);
    k_gemm<6, false><<<dim3(128, 12, 2), 256, 0, stream>>>(y0b, 192, wpin, nullptr, g0b, nullptr, 768);
    k_dw_gelu2<<<NB * 384 * 4, 256, 0, stream>>>(g0b, w_dw, ybufb);
    k_gemm<12, true><<<dim3(128, 3, 2), 256, 0, stream>>>(ybufb, 384, wpout, x1, nullptr, out, 192);
    k_copy<<<2, 256, 0, stream>>>(k_v, out + (size_t)NB * CDIM * HW);
}

// Round 4
// 268.567 us; speedup vs baseline: 5.3610x; 1.1205x over previous
//
#include <hip/hip_runtime.h>
#include <math.h>

#define HW 16384
#define IMG 128
#define CDIM 192
#define C3 144
#define C4 48
#define NB 2
#define NPX 32768   // NB*HW
#define HEADS 6

typedef unsigned short u16;
typedef unsigned int u32;
typedef __attribute__((ext_vector_type(8))) short bf16x8;
typedef __attribute__((ext_vector_type(4))) float f32x4;

__device__ __forceinline__ float bf2f(u16 u) {
    return __uint_as_float(((unsigned int)u) << 16);
}
__device__ __forceinline__ u16 f2bf(float f) {
    unsigned int x = __float_as_uint(f);
    unsigned int r = x + 0x7fffu + ((x >> 16) & 1u);  // RNE
    return (u16)(r >> 16);
}

static inline float* wsf(void* ws, size_t off) { return (float*)((char*)ws + off); }
static inline u16* wsh(void* ws, size_t off) { return (u16*)((char*)ws + off); }

// ---------------- K0: setup = weight bf16 conversion + tiny GEMVs + k_v copy -
// wb layout: wq[192][160] | wkv[384][64] | wpo[192][192] | wpin[768][192] | wpout[192][384]
__global__ void k_setup(const float* __restrict__ kvv, const float* __restrict__ wkR,
                        const float* __restrict__ wkI, const float* __restrict__ wffk,
                        const float* __restrict__ wqR, const float* __restrict__ wkvI,
                        const float* __restrict__ wpo, const float* __restrict__ wpin,
                        const float* __restrict__ wpout,
                        u16* __restrict__ wb, float* __restrict__ sm,
                        float* __restrict__ tail) {
    int t = blockIdx.x * 256 + threadIdx.x;
    if (t < 313344) {
        float v;
        if (t < 30720) {
            int o = t / 160, i = t % 160;
            v = (i < 144) ? wqR[o * 144 + i] : 0.f;
        } else if (t < 55296) {
            int r = t - 30720; int o = r / 64, i = r % 64;
            v = (i < 48) ? wkvI[o * 48 + i] : 0.f;
        } else if (t < 92160) {
            v = wpo[t - 55296];
        } else if (t < 239616) {
            v = wpin[t - 92160];
        } else {
            v = wpout[t - 239616];
        }
        wb[t] = f2bf(v);
    } else if (t < 314112) {
        int r = t - 313344;              // 0..767: modulation GEMVs (stored as val+1)
        if (r < 288) {
            int b = r / 144, o = r % 144;
            const float* v = kvv + b * 256;
            const float* w = wkR + o * 192;
            float s = 0.f;
            for (int j = 0; j < 192; j++) s += v[j] * w[j];
            sm[r] = s + 1.0f;
        } else if (r < 384) {
            int r2 = r - 288;
            int b = r2 / 48, o = r2 % 48;
            const float* v = kvv + b * 256 + 192;
            const float* w = wkI + o * 64;
            float s = 0.f;
            for (int j = 0; j < 64; j++) s += v[j] * w[j];
            sm[288 + r2] = s + 1.0f;
        } else {
            int r2 = r - 384;
            int b = r2 / 192, o = r2 % 192;
            const float* v = kvv + b * 256;
            const float* w = wffk + o * 256;
            float s = 0.f;
            for (int j = 0; j < 256; j++) s += v[j] * w[j];
            sm[384 + r2] = s + 1.0f;
        }
    } else if (t < 314624) {
        int r = t - 314112;
        tail[r] = kvv[r];                // k_v pass-through to output tail
    }
}

// ---------------- K1: channel LayerNorm + modulation, single-pass, bf16 out --
// block = 64 pixels (16 float4 groups) x 16 channel-groups(12 ch); 512 blocks.
template <bool INBF, bool SPLIT>
__global__ __launch_bounds__(256) void k_ln(
    const void* __restrict__ xin,
    const float* __restrict__ lnw, const float* __restrict__ lnb,
    const float* __restrict__ sca, const float* __restrict__ scb,
    u16* __restrict__ outA, u16* __restrict__ outB) {
    __shared__ float red[2][16][16][4];
    __shared__ float mu_s[16][4], rstd_s[16][4];
    int t = threadIdx.x;
    int px4 = t & 15, cg = t >> 4;
    int base = blockIdx.x * 64;
    int b = base >> 14;
    int p = (base & 16383) + px4 * 4;
    float vals[12][4];
    float s[4] = {0.f, 0.f, 0.f, 0.f}, s2[4] = {0.f, 0.f, 0.f, 0.f};
#pragma unroll
    for (int j = 0; j < 12; j++) {
        int c = cg * 12 + j;
        size_t off = ((size_t)(b * CDIM + c)) * HW + p;
        float v[4];
        if (INBF) {
            ushort4 u = *(const ushort4*)((const u16*)xin + off);
            v[0] = bf2f(u.x); v[1] = bf2f(u.y); v[2] = bf2f(u.z); v[3] = bf2f(u.w);
        } else {
            float4 f = *(const float4*)((const float*)xin + off);
            v[0] = f.x; v[1] = f.y; v[2] = f.z; v[3] = f.w;
        }
#pragma unroll
        for (int q = 0; q < 4; q++) {
            vals[j][q] = v[q]; s[q] += v[q]; s2[q] += v[q] * v[q];
        }
    }
#pragma unroll
    for (int q = 0; q < 4; q++) { red[0][cg][px4][q] = s[q]; red[1][cg][px4][q] = s2[q]; }
    __syncthreads();
    if (t < 16) {
        float S[4] = {0.f, 0.f, 0.f, 0.f}, S2[4] = {0.f, 0.f, 0.f, 0.f};
        for (int g2 = 0; g2 < 16; g2++)
#pragma unroll
            for (int q = 0; q < 4; q++) { S[q] += red[0][g2][t][q]; S2[q] += red[1][g2][t][q]; }
#pragma unroll
        for (int q = 0; q < 4; q++) {
            float mu = S[q] * (1.0f / CDIM);
            float var = S2[q] * (1.0f / CDIM) - mu * mu;
            mu_s[t][q] = mu;
            rstd_s[t][q] = rsqrtf(var + 1e-5f);
        }
    }
    __syncthreads();
    float mu[4], rs[4];
#pragma unroll
    for (int q = 0; q < 4; q++) { mu[q] = mu_s[px4][q]; rs[q] = rstd_s[px4][q]; }
#pragma unroll
    for (int j = 0; j < 12; j++) {
        int c = cg * 12 + j;
        float w = lnw[c], bb = lnb[c];
        float sc; u16* op; size_t off;
        if (SPLIT) {
            if (c < C3) { sc = sca[b * C3 + c]; off = ((size_t)(b * C3 + c)) * HW + p; op = outA; }
            else { sc = scb[b * C4 + c - C3]; off = ((size_t)(b * C4 + c - C3)) * HW + p; op = outB; }
        } else {
            sc = sca[b * CDIM + c]; off = ((size_t)(b * CDIM + c)) * HW + p; op = outA;
        }
        ushort4 o;
        o.x = f2bf(((vals[j][0] - mu[0]) * rs[0] * w + bb) * sc);
        o.y = f2bf(((vals[j][1] - mu[1]) * rs[1] * w + bb) * sc);
        o.z = f2bf(((vals[j][2] - mu[2]) * rs[2] * w + bb) * sc);
        o.w = f2bf(((vals[j][3] - mu[3]) * rs[3] * w + bb) * sc);
        *(ushort4*)(op + off) = o;
    }
}

// ---------------- K2: conv1x1 as bf16 MFMA GEMM ------------------------------
// out[b][m][n] = sum_k W[m][k]*X[b][k][n]; M=CO, N=HW(128/tile), K=NCH*32.
// W zero-padded to K (X overreads are garbage*0; slack reserved).
// MODE 0: out bf16. MODE 1: resid fp32, out bf16. MODE 2: resid bf16, out fp32.
template <int NCH, int MODE>
__global__ __launch_bounds__(256) void k_gemm(
    const u16* __restrict__ X, int xrows,
    const u16* __restrict__ Wb,
    const void* __restrict__ resid, void* __restrict__ outp, int CO) {
    constexpr int CIP = NCH * 32;
    __shared__ __align__(16) u16 Ws[64 * 32];
    __shared__ __align__(16) u16 Xs[32 * 130];
    const int tid = threadIdx.x;
    const int n0 = blockIdx.x * 128;
    const int m0 = blockIdx.y * 64;
    const int b = blockIdx.z;
    const u16* Xb = X + (size_t)b * xrows * HW + n0;
    const int wave = tid >> 6, lane = tid & 63;
    const int quad = lane >> 4, l16 = lane & 15;
    const int smr = tid >> 2, sk4 = tid & 3;
    const int skr = tid >> 3, sc0 = (tid & 7) * 16;
    f32x4 acc[4][2] = {};
    for (int ch = 0; ch < NCH; ch++) {
        const int k0 = ch * 32;
        if (ch) __syncthreads();
        {
            const int4 wv = *(const int4*)(Wb + (size_t)(m0 + smr) * CIP + k0 + sk4 * 8);
            *(int4*)&Ws[(smr << 5) + (((sk4 ^ (smr & 3)) & 3) << 3)] = wv;
        }
        {
            const u16* xc = Xb + (size_t)(k0 + skr) * HW + sc0;
            int4 r0 = *(const int4*)xc;
            int4 r1 = *(const int4*)(xc + 8);
            u32* dst = (u32*)&Xs[skr * 130 + sc0];
#pragma unroll
            for (int i = 0; i < 4; i++) dst[i] = ((const u32*)&r0)[i];
#pragma unroll
            for (int i = 0; i < 4; i++) dst[4 + i] = ((const u32*)&r1)[i];
        }
        __syncthreads();
        bf16x8 af[4];
#pragma unroll
        for (int mi = 0; mi < 4; mi++) {
            int row = mi * 16 + l16;
            af[mi] = *(const bf16x8*)&Ws[(row << 5) + ((quad ^ (row & 3)) << 3)];
        }
#pragma unroll
        for (int ni = 0; ni < 2; ni++) {
            int n = wave * 32 + ni * 16 + l16;
            bf16x8 bfr;
#pragma unroll
            for (int j = 0; j < 8; j++) bfr[j] = (short)Xs[(quad * 8 + j) * 130 + n];
#pragma unroll
            for (int mi = 0; mi < 4; mi++)
                acc[mi][ni] = __builtin_amdgcn_mfma_f32_16x16x32_bf16(af[mi], bfr, acc[mi][ni], 0, 0, 0);
        }
    }
#pragma unroll
    for (int mi = 0; mi < 4; mi++) {
#pragma unroll
        for (int ni = 0; ni < 2; ni++) {
#pragma unroll
            for (int r = 0; r < 4; r++) {
                int m = m0 + mi * 16 + quad * 4 + r;
                int n = n0 + wave * 32 + ni * 16 + l16;
                size_t idx = ((size_t)b * CO + m) * HW + n;
                float v = acc[mi][ni][r];
                if (MODE == 0) {
                    ((u16*)outp)[idx] = f2bf(v);
                } else if (MODE == 1) {
                    v += ((const float*)resid)[idx];
                    ((u16*)outp)[idx] = f2bf(v);
                } else {
                    v += bf2f(((const u16*)resid)[idx]);
                    ((float*)outp)[idx] = v;
                }
            }
        }
    }
}

// ---------------- K3: depthwise 3x3, LDS-tiled, fused sumsq partials ---------
__global__ __launch_bounds__(256) void k_dw2(const u16* __restrict__ X,
                                             const float* __restrict__ Wd,
                                             u16* __restrict__ out, int C, int sqCh,
                                             float* __restrict__ sqp) {
    __shared__ float In[34 * 132];
    __shared__ float red[4];
    int bc = blockIdx.x >> 2, rt = blockIdx.x & 3;
    int b = bc / C, ch = bc % C;
    const u16* xb = X + (size_t)bc * HW;
    int t = threadIdx.x;
    int c0 = (t & 7) * 16;
    for (int r = t >> 3; r < 34; r += 32) {
        int y = rt * 32 - 1 + r;
        float* dst = &In[r * 132 + 1 + c0];
        if ((unsigned)y < 128u) {
            const u16* src = xb + y * 128 + c0;
            int4 r0 = *(const int4*)src;
            int4 r1 = *(const int4*)(src + 8);
            const u16* p0 = (const u16*)&r0;
            const u16* p1 = (const u16*)&r1;
#pragma unroll
            for (int i = 0; i < 8; i++) dst[i] = bf2f(p0[i]);
#pragma unroll
            for (int i = 0; i < 8; i++) dst[8 + i] = bf2f(p1[i]);
        } else {
#pragma unroll
            for (int i = 0; i < 16; i++) dst[i] = 0.f;
        }
    }
    if (t < 34) { In[t * 132] = 0.f; In[t * 132 + 129] = 0.f; }
    __syncthreads();
    const float* w = Wd + ch * 9;
    float w00 = w[0], w01 = w[1], w02 = w[2], w10 = w[3], w11 = w[4],
          w12 = w[5], w20 = w[6], w21 = w[7], w22 = w[8];
    int x = t & 127, rg = t >> 7;
    int base = rg * 16;
    float A2 = 0.f, A1 = 0.f, B1 = 0.f, ssq = 0.f;
    u16* ob = out + (size_t)bc * HW + (rt * 32 + base) * 128 + x;
#pragma unroll
    for (int r = 0; r < 18; r++) {
        const float* row = &In[(base + r) * 132 + x];
        float v0 = row[0], v1 = row[1], v2 = row[2];
        float h0 = w00 * v0 + w01 * v1 + w02 * v2;
        float h1 = w10 * v0 + w11 * v1 + w12 * v2;
        float h2 = w20 * v0 + w21 * v1 + w22 * v2;
        if (r >= 2) {
            float val = A2 + B1 + h2;
            ob[(size_t)(r - 2) * 128] = f2bf(val);
            ssq += val * val;
        }
        A2 = A1; A1 = h0; B1 = h1;
    }
    if (ch < sqCh) {   // block-uniform branch
        for (int o = 32; o > 0; o >>= 1) ssq += __shfl_down(ssq, o, 64);
        int wid = t >> 6, lane = t & 63;
        if (lane == 0) red[wid] = ssq;
        __syncthreads();
        if (t == 0) sqp[((b * 192 + ch) << 2) | rt] = red[0] + red[1] + red[2] + red[3];
    }
}

// ---------------- K3b: depthwise 3x3 pair + exact GELU gate, LDS-tiled -------
__global__ __launch_bounds__(256) void k_dw_gelu2(const u16* __restrict__ G0,
                                                  const float* __restrict__ Wd,
                                                  u16* __restrict__ out) {
    __shared__ float In[2 * 34 * 132];
    int bc = blockIdx.x >> 2, rt = blockIdx.x & 3;
    int b = bc / 384, j = bc % 384;
    int t = threadIdx.x;
    int c0 = (t & 7) * 16;
    for (int pl = 0; pl < 2; pl++) {
        const u16* xb = G0 + ((size_t)b * 768 + pl * 384 + j) * HW;
        float* pla = &In[pl * 34 * 132];
        for (int r = t >> 3; r < 34; r += 32) {
            int y = rt * 32 - 1 + r;
            float* dst = &pla[r * 132 + 1 + c0];
            if ((unsigned)y < 128u) {
                const u16* src = xb + y * 128 + c0;
                int4 r0 = *(const int4*)src;
                int4 r1 = *(const int4*)(src + 8);
                const u16* p0 = (const u16*)&r0;
                const u16* p1 = (const u16*)&r1;
#pragma unroll
                for (int i = 0; i < 8; i++) dst[i] = bf2f(p0[i]);
#pragma unroll
                for (int i = 0; i < 8; i++) dst[8 + i] = bf2f(p1[i]);
            } else {
#pragma unroll
                for (int i = 0; i < 16; i++) dst[i] = 0.f;
            }
        }
        if (t < 34) { pla[t * 132] = 0.f; pla[t * 132 + 129] = 0.f; }
    }
    __syncthreads();
    const float* w1 = Wd + j * 9;
    const float* w2 = Wd + (384 + j) * 9;
    float a00 = w1[0], a01 = w1[1], a02 = w1[2], a10 = w1[3], a11 = w1[4],
          a12 = w1[5], a20 = w1[6], a21 = w1[7], a22 = w1[8];
    float b00 = w2[0], b01 = w2[1], b02 = w2[2], b10 = w2[3], b11 = w2[4],
          b12 = w2[5], b20 = w2[6], b21 = w2[7], b22 = w2[8];
    int x = t & 127, rg = t >> 7;
    int base = rg * 16;
    float A2a = 0.f, A1a = 0.f, B1a = 0.f;
    float A2b = 0.f, A1b = 0.f, B1b = 0.f;
    u16* ob = out + ((size_t)b * 384 + j) * HW + (rt * 32 + base) * 128 + x;
#pragma unroll
    for (int r = 0; r < 18; r++) {
        const float* r1p = &In[(base + r) * 132 + x];
        const float* r2p = r1p + 34 * 132;
        float u0 = r1p[0], u1 = r1p[1], u2 = r1p[2];
        float v0 = r2p[0], v1 = r2p[1], v2 = r2p[2];
        float h0a = a00 * u0 + a01 * u1 + a02 * u2;
        float h1a = a10 * u0 + a11 * u1 + a12 * u2;
        float h2a = a20 * u0 + a21 * u1 + a22 * u2;
        float h0b = b00 * v0 + b01 * v1 + b02 * v2;
        float h1b = b10 * v0 + b11 * v1 + b12 * v2;
        float h2b = b20 * v0 + b21 * v1 + b22 * v2;
        if (r >= 2) {
            float s1 = A2a + B1a + h2a;
            float s2 = A2b + B1b + h2b;
            float g = 0.5f * s1 * (1.0f + erff(s1 * 0.70710678118654752f));
            ob[(size_t)(r - 2) * 128] = f2bf(g * s2);
        }
        A2a = A1a; A1a = h0a; B1a = h1a;
        A2b = A1b; A1b = h0b; B1b = h1b;
    }
}

// ---------------- K5: S partials = Q*K^T via MFMA, 32 d-chunks, no atomics ---
__global__ __launch_bounds__(256) void k_qk(const u16* __restrict__ qb_,
                                            const u16* __restrict__ kb_,
                                            float* __restrict__ Spart) {
    int bh = blockIdx.x >> 5, ds = blockIdx.x & 31;   // 384 blocks
    int b = bh / HEADS, h = bh % HEADS;
    int tid = threadIdx.x;
    int wave = tid >> 6, lane = tid & 63;
    int quad = lane >> 4, l16 = lane & 15;
    int tm = wave >> 1, tn = wave & 1;
    const u16* qrow = qb_ + ((size_t)(b * 192 + h * 32 + tm * 16 + l16)) * HW + ds * 512 + quad * 8;
    const u16* krow = kb_ + ((size_t)(b * 384 + h * 32 + tn * 16 + l16)) * HW + ds * 512 + quad * 8;
    f32x4 acc = {};
#pragma unroll
    for (int ch = 0; ch < 16; ch++) {
        bf16x8 a = *(const bf16x8*)(qrow + ch * 32);
        bf16x8 k8 = *(const bf16x8*)(krow + ch * 32);
        acc = __builtin_amdgcn_mfma_f32_16x16x32_bf16(a, k8, acc, 0, 0, 0);
    }
    float* Sb = Spart + ((size_t)ds * 12 + bh) * 1024;
#pragma unroll
    for (int r = 0; r < 4; r++)
        Sb[(tm * 16 + quad * 4 + r) * 32 + tn * 16 + l16] = acc[r];
}

// ---------------- K6: reduce partials + normalize + softmax, bf16 out --------
__global__ void k_softmax(const float* __restrict__ Spart, const float* __restrict__ sqqp,
                          const float* __restrict__ sqkp, const float* __restrict__ temp,
                          u16* __restrict__ attnb) {
    int row = blockIdx.x;           // 0..383
    int bh = row >> 5, c2 = row & 31;
    int b = bh / HEADS, h = bh % HEADS;
    int e = threadIdx.x;            // 64 threads, active e<32
    float l = -1e30f;
    if (e < 32) {
        float s = 0.f;
        for (int d = 0; d < 32; d++) s += Spart[((size_t)d * 12 + bh) * 1024 + c2 * 32 + e];
        const float* qp = sqqp + (b * 192 + h * 32 + c2) * 4;
        const float* kp = sqkp + (b * 192 + h * 32 + e) * 4;
        float nq = qp[0] + qp[1] + qp[2] + qp[3];
        float nk = kp[0] + kp[1] + kp[2] + kp[3];
        float invq = 1.0f / fmaxf(sqrtf(nq), 1e-12f);
        float invk = 1.0f / fmaxf(sqrtf(nk), 1e-12f);
        l = s * invq * invk * temp[h];
    }
    float m = l;
    for (int o = 32; o > 0; o >>= 1) m = fmaxf(m, __shfl_xor(m, o, 64));
    float ev = (e < 32) ? expf(l - m) : 0.f;
    float ssum = ev;
    for (int o = 32; o > 0; o >>= 1) ssum += __shfl_xor(ssum, o, 64);
    if (e < 32) attnb[bh * 1024 + c2 * 32 + e] = f2bf(ev / ssum);
}

// ---------------- K7: out = attn @ V via MFMA, V staged [e][p] in LDS --------
__global__ __launch_bounds__(256) void k_av(const u16* __restrict__ attnb,
                                            const u16* __restrict__ kvb,
                                            u16* __restrict__ out) {
    __shared__ __align__(16) u16 Vs[32 * 130];
    int bh = blockIdx.x >> 7;       // 12
    int pt = blockIdx.x & 127;
    int b = bh / HEADS, h = bh % HEADS;
    int p0 = pt * 128;
    int t = threadIdx.x;
    {
        int e = t >> 3, c0 = (t & 7) * 16;
        const u16* src = kvb + ((size_t)(b * 384 + 192 + h * 32 + e)) * HW + p0 + c0;
        int4 r0 = *(const int4*)src;
        int4 r1 = *(const int4*)(src + 8);
        u32* dst = (u32*)&Vs[e * 130 + c0];
#pragma unroll
        for (int i = 0; i < 4; i++) dst[i] = ((const u32*)&r0)[i];
#pragma unroll
        for (int i = 0; i < 4; i++) dst[4 + i] = ((const u32*)&r1)[i];
    }
    __syncthreads();
    int wave = t >> 6, lane = t & 63;
    int quad = lane >> 4, l16 = lane & 15;
    f32x4 acc[2][2] = {};
    bf16x8 af[2];
#pragma unroll
    for (int tm = 0; tm < 2; tm++)
        af[tm] = *(const bf16x8*)(attnb + bh * 1024 + (tm * 16 + l16) * 32 + quad * 8);
#pragma unroll
    for (int nt = 0; nt < 2; nt++) {
        int n = wave * 32 + nt * 16 + l16;
        bf16x8 bfr;
#pragma unroll
        for (int j = 0; j < 8; j++) bfr[j] = (short)Vs[(quad * 8 + j) * 130 + n];
#pragma unroll
        for (int tm = 0; tm < 2; tm++)
            acc[tm][nt] = __builtin_amdgcn_mfma_f32_16x16x32_bf16(af[tm], bfr, acc[tm][nt], 0, 0, 0);
    }
#pragma unroll
    for (int tm = 0; tm < 2; tm++)
#pragma unroll
        for (int nt = 0; nt < 2; nt++)
#pragma unroll
            for (int r = 0; r < 4; r++) {
                int c = h * 32 + tm * 16 + quad * 4 + r;
                int p = p0 + wave * 32 + nt * 16 + l16;
                out[((size_t)b * 192 + c) * HW + p] = f2bf(acc[tm][nt][r]);
            }
}

extern "C" void kernel_launch(void* const* d_in, const int* in_sizes, int n_in,
                              void* d_out, int out_size, void* d_ws, size_t ws_size,
                              hipStream_t stream) {
    const float* x     = (const float*)d_in[0];
    const float* k_v   = (const float*)d_in[1];
    const float* ln1w  = (const float*)d_in[2];
    const float* ln1b  = (const float*)d_in[3];
    const float* temp  = (const float*)d_in[4];
    const float* w_kR  = (const float*)d_in[5];
    const float* w_kI  = (const float*)d_in[6];
    const float* w_qR  = (const float*)d_in[7];
    const float* w_qdw = (const float*)d_in[8];
    const float* w_kvI = (const float*)d_in[9];
    const float* w_kvdw= (const float*)d_in[10];
    const float* w_po  = (const float*)d_in[11];
    const float* ln2w  = (const float*)d_in[12];
    const float* ln2b  = (const float*)d_in[13];
    const float* w_ffk = (const float*)d_in[14];
    const float* w_pin = (const float*)d_in[15];
    const float* w_dw  = (const float*)d_in[16];
    const float* w_pout= (const float*)d_in[17];
    float* out = (float*)d_out;

    const size_t MiB = 1048576ULL;
    // Region plan (disjoint lifetimes; peak ~150 MiB):
    u16*   q0b     = wsh(d_ws, 0);          // [2][192] bf16; reused: attnout, y0
    u16*   attnoutb= wsh(d_ws, 0);
    u16*   y0b     = wsh(d_ws, 0);
    u16*   kv0b    = wsh(d_ws, 12 * MiB);   // [2][384] bf16; reused: ybuf
    u16*   ybufb   = wsh(d_ws, 12 * MiB);
    u16*   x1b     = wsh(d_ws, 36 * MiB);   // [2][192] bf16 (po->pout)
    u16*   qbuf_b  = wsh(d_ws, 48 * MiB);   // [2][192] bf16 (dwq->qk)
    u16*   kvbuf_b = wsh(d_ws, 60 * MiB);   // [2][384] bf16 (dwkv->av)
    u16*   xrb     = wsh(d_ws, 84 * MiB);   // [2][144] bf16 + K-pad overread slack
    u16*   xib     = wsh(d_ws, 94 * MiB);   // [2][48] bf16 + slack
    u16*   g0b     = wsh(d_ws, 98 * MiB);   // [2][768] bf16 (pin->gelu)
    u16*   wb      = wsh(d_ws, 146 * MiB);  // bf16 weights, 627 KB
    float* sm      = wsf(d_ws, 147 * MiB);  // smalls
    float* Spart   = wsf(d_ws, 148 * MiB);  // 32*12*1024 fp32 = 1.5 MiB
    u16* wq   = wb;            // [192][160]
    u16* wkv  = wb + 30720;    // [384][64]
    u16* wpo  = wb + 55296;    // [192][192]
    u16* wpin = wb + 92160;    // [768][192]
    u16* wpout= wb + 239616;   // [192][384]
    float* kvr  = sm;               // 288
    float* kvi  = sm + 288;         // 96
    float* kvf  = sm + 384;         // 384
    float* sqqp = sm + 768;         // 1536 (4 row-tile partials x 384 rows)
    float* sqkp = sm + 2304;        // 1536
    u16*   attnb= (u16*)(sm + 3840);// 12288 bf16

    k_setup<<<1229, 256, 0, stream>>>(k_v, w_kR, w_kI, w_ffk, w_qR, w_kvI, w_po,
                                      w_pin, w_pout, wb, sm,
                                      out + (size_t)NB * CDIM * HW);
    k_ln<false, true><<<NPX / 64, 256, 0, stream>>>(x, ln1w, ln1b, kvr, kvi, xrb, xib);
    k_gemm<5, 0><<<dim3(128, 3, 2), 256, 0, stream>>>(xrb, 144, wq, nullptr, q0b, 192);
    k_gemm<2, 0><<<dim3(128, 6, 2), 256, 0, stream>>>(xib, 48, wkv, nullptr, kv0b, 384);
    k_dw2<<<NB * 192 * 4, 256, 0, stream>>>(q0b, w_qdw, qbuf_b, 192, 192, sqqp);
    k_dw2<<<NB * 384 * 4, 256, 0, stream>>>(kv0b, w_kvdw, kvbuf_b, 384, 192, sqkp);
    k_qk<<<12 * 32, 256, 0, stream>>>(qbuf_b, kvbuf_b, Spart);
    k_softmax<<<384, 64, 0, stream>>>(Spart, sqqp, sqkp, temp, attnb);
    k_av<<<12 * 128, 256, 0, stream>>>(attnb, kvbuf_b, attnoutb);
    k_gemm<6, 1><<<dim3(128, 3, 2), 256, 0, stream>>>(attnoutb, 192, wpo, x, x1b, 192);
    k_ln<true, false><<<NPX / 64, 256, 0, stream>>>(x1b, ln2w, ln2b, kvf, nullptr, y0b, nullptr);
    k_gemm<6, 0><<<dim3(128, 12, 2), 256, 0, stream>>>(y0b, 192, wpin, nullptr, g0b, 768);
    k_dw_gelu2<<<NB * 384 * 4, 256, 0, stream>>>(g0b, w_dw, ybufb);
    k_gemm<12, 2><<<dim3(128, 3, 2), 256, 0, stream>>>(ybufb, 384, wpout, x1b, out, 192);
}